// Round 5
// baseline (1099.427 us; speedup 1.0000x reference)
//
#include <hip/hip_runtime.h>
#include <hip/hip_fp16.h>

// Problem constants
#define BB 16
#define MAX_ITER 100

constexpr float EPS_F    = 0.1f;
constexpr float INV_EPS  = 10.0f;
constexpr float MU_P     = 0.0009765625f + 1e-8f;      // 1/1024 + 1e-8  (== nu)
constexpr float LOG_MU   = -6.9314615656526045f;       // log(MU_P)
constexpr float THRESH_B = 1.6f;                        // THRESH(0.1) * B(16)

#define SCOPE_AGENT __HIP_MEMORY_SCOPE_AGENT

typedef _Float16 h2t __attribute__((ext_vector_type(2)));

// v_dot2_f32_f16: a.x*b.x + a.y*b.y + c with f32 accumulation (products exact).
#if __has_builtin(__builtin_amdgcn_fdot2)
__device__ __forceinline__ float fdot2f(h2t a, h2t b, float c) {
    return __builtin_amdgcn_fdot2(a, b, c, false);
}
#else
__device__ __forceinline__ float fdot2f(h2t a, h2t b, float c) {
    return fmaf((float)a[0], (float)b[0], fmaf((float)a[1], (float)b[1], c));
}
#endif

__device__ __forceinline__ h2t pack_rn(float x, float y) {
    union { __half2 a; h2t b; } u;
    u.a = __floats2half2_rn(x, y);
    return u.b;
}
#if __has_builtin(__builtin_amdgcn_cvt_pkrtz)
// cvt_pkrtz returns __fp16x2; bit-cast to our h2t (round-4 compile fix).
__device__ __forceinline__ h2t pack_rz(float x, float y) {
    typedef __fp16 fp16v2 __attribute__((ext_vector_type(2)));
    union { fp16v2 a; h2t b; } u;
    u.a = __builtin_amdgcn_cvt_pkrtz(x, y);    // 1 instr; rtz bias on wv/wu is
    return u.b;                                 // a uniform scale -> pi-invariant
}
#else
__device__ __forceinline__ h2t pack_rz(float x, float y) { return pack_rn(x, y); }
#endif

// Coherent (agent-scope) primitives — validated rounds 0-3.
__device__ __forceinline__ float coh_loadf(float* p) {
    return __hip_atomic_load(p, __ATOMIC_RELAXED, SCOPE_AGENT);
}
__device__ __forceinline__ int coh_loadi(int* p) {
    return __hip_atomic_load(p, __ATOMIC_RELAXED, SCOPE_AGENT);
}
__device__ __forceinline__ void coh_storef(float* p, float v) {
    atomicExch(p, v);
}

// 16-block per-batch barrier, sequence-numbered (target = 16 * seq).
__device__ __forceinline__ void batch_sync(int* cnt, int target) {
    __syncthreads();
    if (threadIdx.x == 0) {
        atomicAdd(cnt, 1);
        while (coh_loadi(cnt) < target) __builtin_amdgcn_s_sleep(1);
    }
    __syncthreads();
}

// ---------------------------------------------------------------------------
// K1: zero Tpart + counters (72992 dwords, contiguous) and out[0:16].
__global__ __launch_bounds__(1024) void init_kernel(
    int* __restrict__ zr, float* __restrict__ outCost)
{
    int gid = blockIdx.x * 1024 + threadIdx.x;
    if (gid < 72992) zr[gid] = 0;            // 0x0 == 0.0f for the float parts
    if (gid < BB)    outCost[gid] = 0.f;
}

// ---------------------------------------------------------------------------
// K2: Sinkhorn loop + fused epilogue. 256 blocks x 1024 threads, 1 block/CU.
// vs round 3 (which measured ~85us for the loop):
//  - dot pass: v_dot2_f32_f16 on packed fp16 (E pairs already packed; wv
//    packed per iter) — kills all fp16->f32 unpacks and halves the fmas.
//  - column pass: transposed register fragment eT (4 cols x 16 rows as
//    row-pair h2, +32 VGPR, loaded once from L3-hot C) + dot2 against packed
//    wu; 16KB colpart[4][1028] exchange replaces the 65KB part[16] exchange.
//  - epilogue (pi/outC/cost) fused here: u_prev is in registers, v comes from
//    t_last via LDS; cost via ONE atomicAdd per block (16/address — not the
//    round-2 16384/address mistake). Deletes 2 kernel launches + u/v globals.
__global__ __launch_bounds__(1024, 4) void sink_iter(
    const float* __restrict__ C, float* __restrict__ Tpart,
    float* __restrict__ errB, float* __restrict__ errTot,
    int* __restrict__ errCnt, int* __restrict__ bsync,
    float* __restrict__ outPi, float* __restrict__ outC,
    float* __restrict__ outCost)
{
    const int tid  = threadIdx.x;
    const int lane = tid & 63;
    const int wav  = tid >> 6;            // 0..15
    const int blk  = blockIdx.x;          // 0..255
    // XCD-grouped mapping (blk%8 ~ XCD): each batch's 16 blocks share one L2.
    const int slot = blk >> 3;            // 0..31
    const int b    = ((blk & 7) << 1) | (slot >> 4);
    const int sub  = slot & 15;

    const float* Cb = C + ((size_t)b << 20);
    float* Tb  = Tpart + (b << 12);       // [4][1024] per batch
    int*   bs  = bsync + (b << 4);

    __shared__ float colpart[4][1028];    // col partials by 16-row group
    __shared__ float wv_lds[1024];        // wv f32, XOR-swizzled (round-3 proven)
    __shared__ h2t   wu_h2[32];           // packed wu row-pairs for this block
    __shared__ float werr[16];
    __shared__ float errv_s;

    // ---- prologue A: row fragment e[4][8] — rows wav*4+r, cols [16*lane..) -
    h2t e[4][8];
    #pragma unroll
    for (int r = 0; r < 4; ++r) {
        const float4* C4 = (const float4*)(
            Cb + (((size_t)((sub << 6) + (wav << 2) + r)) << 10) + (lane << 4));
        float4 c0 = C4[0], c1 = C4[1], c2 = C4[2], c3 = C4[3];
        e[r][0] = pack_rn(__expf(-INV_EPS*c0.x), __expf(-INV_EPS*c0.y));
        e[r][1] = pack_rn(__expf(-INV_EPS*c0.z), __expf(-INV_EPS*c0.w));
        e[r][2] = pack_rn(__expf(-INV_EPS*c1.x), __expf(-INV_EPS*c1.y));
        e[r][3] = pack_rn(__expf(-INV_EPS*c1.z), __expf(-INV_EPS*c1.w));
        e[r][4] = pack_rn(__expf(-INV_EPS*c2.x), __expf(-INV_EPS*c2.y));
        e[r][5] = pack_rn(__expf(-INV_EPS*c2.z), __expf(-INV_EPS*c2.w));
        e[r][6] = pack_rn(__expf(-INV_EPS*c3.x), __expf(-INV_EPS*c3.y));
        e[r][7] = pack_rn(__expf(-INV_EPS*c3.z), __expf(-INV_EPS*c3.w));
    }

    // ---- prologue B: transposed fragment eT[4][8] — cols cg..cg+3, 16 rows -
    // eT[cc][k] = (E[r0+2k][cg+cc], E[r0+2k+1][cg+cc]) ; coalesced re-read of
    // the block's C slice (L2/L3-hot from prologue A).
    const int cg = (tid & 255) << 2;      // col base
    const int r0 = (tid >> 8) << 4;       // local row base (0/16/32/48)
    h2t eT[4][8];
    #pragma unroll
    for (int k = 0; k < 8; ++k) {
        const float* p0 = Cb + (((size_t)((sub << 6) + r0 + 2*k)) << 10) + cg;
        float4 a = *(const float4*)p0;
        float4 d = *(const float4*)(p0 + 1024);
        eT[0][k] = pack_rn(__expf(-INV_EPS*a.x), __expf(-INV_EPS*d.x));
        eT[1][k] = pack_rn(__expf(-INV_EPS*a.y), __expf(-INV_EPS*d.y));
        eT[2][k] = pack_rn(__expf(-INV_EPS*a.z), __expf(-INV_EPS*d.z));
        eT[3][k] = pack_rn(__expf(-INV_EPS*a.w), __expf(-INV_EPS*d.w));
    }

    float u_prev[4] = {0.f, 0.f, 0.f, 0.f};
    float t_last = 1.0f;                  // final column total for col==tid
    wv_lds[tid] = 1.0f;                   // wv0 = 1 (uniform: swizzle moot)
    __syncthreads();

    for (int it = 0; it < MAX_ITER; ++it) {
        const int q = it & 3;

        // ---- wf: wv cols [16*lane..+16) from swizzled LDS, packed to h2 ----
        h2t wfh[8];
        #pragma unroll
        for (int j = 0; j < 4; ++j) {
            int idx = ((lane << 4) | (j << 2)) ^ ((lane & 7) << 2);
            float4 t4 = *(const float4*)&wv_lds[idx];
            wfh[2*j]   = pack_rz(t4.x, t4.y);
            wfh[2*j+1] = pack_rz(t4.z, t4.w);
        }

        // ---- dot pass: s[r] = E_row . wv via dot2 (f32 accumulate) --------
        float s0 = 0.f, s1 = 0.f, s2 = 0.f, s3 = 0.f;
        #pragma unroll
        for (int j = 0; j < 8; ++j) {
            s0 = fdot2f(e[0][j], wfh[j], s0);
            s1 = fdot2f(e[1][j], wfh[j], s1);
            s2 = fdot2f(e[2][j], wfh[j], s2);
            s3 = fdot2f(e[3][j], wfh[j], s3);
        }
        float derr = 0.f;
        float wuv[4];
        {
            float sr[4] = {s0, s1, s2, s3};
            #pragma unroll
            for (int r = 0; r < 4; ++r) {
                float s = sr[r];
                #pragma unroll
                for (int off = 32; off >= 1; off >>= 1) s += __shfl_xor(s, off);
                float un = EPS_F * (LOG_MU - __logf(s));
                derr += fabsf(un - u_prev[r]);
                u_prev[r] = un;
                wuv[r] = MU_P / s;        // exp(u_new/eps), uniform across wave
            }
        }
        if (lane == 0) {
            werr[wav] = derr;
            wu_h2[2*wav]   = pack_rz(wuv[0], wuv[1]);
            wu_h2[2*wav+1] = pack_rz(wuv[2], wuv[3]);
        }
        __syncthreads();                   // wu_h2 + werr visible

        // ---- column pass: accT[cc] = sum_r E[r][cg+cc]*wu[r] via dot2 -----
        float a0 = 0.f, a1 = 0.f, a2 = 0.f, a3 = 0.f;
        {
            const int kb = (tid >> 8) << 3;
            #pragma unroll
            for (int k = 0; k < 8; ++k) {
                h2t wk = wu_h2[kb + k];    // broadcast read (uniform per wave)
                a0 = fdot2f(eT[0][k], wk, a0);
                a1 = fdot2f(eT[1][k], wk, a1);
                a2 = fdot2f(eT[2][k], wk, a2);
                a3 = fdot2f(eT[3][k], wk, a3);
            }
            *(float4*)&colpart[tid >> 8][cg] = make_float4(a0, a1, a2, a3);
        }
        // block err -> per-batch err (RMW)
        if (wav == 0) {
            float ev = (lane < 16) ? werr[lane] : 0.f;
            #pragma unroll
            for (int off = 8; off >= 1; off >>= 1) ev += __shfl_xor(ev, off);
            if (lane == 0) atomicAdd(&errB[(((it << 4) + b) << 2)], ev);
        }
        __syncthreads();                   // colpart complete

        // 4-group reduce (ascending) -> block col partial -> shared total
        {
            float ts = colpart[0][tid] + colpart[1][tid]
                     + colpart[2][tid] + colpart[3][tid];
            atomicAdd(&Tb[(q << 10) | tid], ts);
        }

        batch_sync(bs, (it + 1) << 4);     // the ONLY inter-block sync

        // zero our 64-col slice of buffer (it+2)&3 for its reuse at it+2
        if (tid < 64)
            coh_storef(&Tb[(((it + 2) & 3) << 10) | ((sub << 6) + tid)], 0.f);

        // batch err complete -> publish to global (overlaps with v-update)
        if (sub == 0 && tid == 0) {
            float eb = coh_loadf(&errB[(((it << 4) + b) << 2)]);
            atomicAdd(&errTot[it << 2], eb);
            __threadfence();               // order errTot before errCnt
            atomicAdd(&errCnt[it << 2], 1);
        }

        // ---- v-update: ONE coherent load of the final column total --------
        {
            float t = coh_loadf(&Tb[(q << 10) | tid]);
            t_last = t;
            wv_lds[tid ^ (((tid >> 4) & 7) << 2)] = MU_P / t;
        }
        __syncthreads();

        // ---- break check: one-sided wait for all 16 batch publications ----
        if (tid == 0) {
            while (coh_loadi(&errCnt[it << 2]) < 16) __builtin_amdgcn_s_sleep(1);
            errv_s = coh_loadf(&errTot[it << 2]);
        }
        __syncthreads();
        if (errv_s < THRESH_B) break;      // uniform across the grid
    }

    // ======== fused epilogue: pi, C copy, cost ==============================
    // v per column from t_last (thread tid holds the total for col tid).
    colpart[0][tid] = EPS_F * (LOG_MU - __logf(t_last));
    __syncthreads();

    float cp = 0.f;
    #pragma unroll
    for (int r = 0; r < 4; ++r) {
        const int grow = (sub << 6) + (wav << 2) + r;
        const size_t rb = ((size_t)b << 20) + ((size_t)grow << 10);
        const float ui = u_prev[r];
        #pragma unroll
        for (int ch = 0; ch < 4; ++ch) {
            const int col = (ch << 8) | (lane << 2);
            float4 c  = *(const float4*)(C + rb + col);
            float4 vv = *(const float4*)&colpart[0][col];
            float4 p;
            p.x = __expf((ui + vv.x - c.x) * INV_EPS);
            p.y = __expf((ui + vv.y - c.y) * INV_EPS);
            p.z = __expf((ui + vv.z - c.z) * INV_EPS);
            p.w = __expf((ui + vv.w - c.w) * INV_EPS);
            *(float4*)(outPi + rb + col) = p;
            *(float4*)(outC  + rb + col) = c;
            cp += p.x*c.x + p.y*c.y + p.z*c.z + p.w*c.w;
        }
    }
    #pragma unroll
    for (int off = 32; off >= 1; off >>= 1) cp += __shfl_xor(cp, off);
    if (lane == 0) werr[wav] = cp;
    __syncthreads();
    if (wav == 0) {
        float ev = (lane < 16) ? werr[lane] : 0.f;
        #pragma unroll
        for (int off = 8; off >= 1; off >>= 1) ev += __shfl_xor(ev, off);
        if (lane == 0) atomicAdd(&outCost[b], ev);   // 16 adds/address: cheap
    }
}

// ---------------------------------------------------------------------------
extern "C" void kernel_launch(void* const* d_in, const int* in_sizes, int n_in,
                              void* d_out, int out_size, void* d_ws, size_t ws_size,
                              hipStream_t stream)
{
    const float* C = (const float*)d_in[2];   // x,y unused (shapes only)
    float* out = (float*)d_out;

    // ws layout (~0.3 MB): Tpart + counters, contiguous for init zeroing.
    float* Tpart  = (float*)d_ws;             // 4*1024*16 = 65536 (4-deep accum)
    float* errB   = Tpart + 65536;            // 6400  (stride-4 [it][b])
    float* errTot = errB + 6400;              // 400   (stride-4 [it])
    int*   errCnt = (int*)(errTot + 400);     // 400
    int*   bsync  = errCnt + 400;             // 256   (stride-16 [b])
    // Tpart..bsync contiguous: 72992 dwords zeroed by init_kernel.

    float* outPi = out + 16;
    float* outC  = out + 16 + (size_t)16777216;

    init_kernel<<<72, 1024, 0, stream>>>((int*)Tpart, out);

    void* args[] = { (void*)&C, (void*)&Tpart,
                     (void*)&errB, (void*)&errTot, (void*)&errCnt, (void*)&bsync,
                     (void*)&outPi, (void*)&outC, (void*)&out };
    hipLaunchCooperativeKernel((void*)sink_iter, dim3(256), dim3(1024),
                               args, 0, stream);
}